// Round 4
// baseline (365.147 us; speedup 1.0000x reference)
//
#include <hip/hip_runtime.h>
#include <math.h>

#define DIMD 1024
#define CHUNKLEN 64
#define NTOK 16384   // B*S = 4*4096

#define TM 128
#define TN 128
#define BK 64

#define INV2PI 0.15915494309189535f

typedef __bf16 bf16x8 __attribute__((ext_vector_type(8)));
typedef float floatx4 __attribute__((ext_vector_type(4)));
typedef unsigned short ushort8v __attribute__((ext_vector_type(8)));

__device__ __forceinline__ float bf2f(unsigned short u) {
  union { unsigned int i; float f; } v; v.i = ((unsigned int)u) << 16; return v.f;
}
__device__ __forceinline__ unsigned short f2bf(float f) {
  union { float f; unsigned int i; } v; v.f = f;
  unsigned int r = v.i + 0x7FFFu + ((v.i >> 16) & 1u);
  return (unsigned short)(r >> 16);
}

// tanh(v) = 1 - 2/(e^{2v}+1); exp->inf gives 1, exp->0 gives -1 (no NaN).
__device__ __forceinline__ float tanh_fast(float v) {
  const float t = __expf(2.0f * v);
  return 1.0f - 2.0f * __builtin_amdgcn_rcpf(t + 1.0f);
}

__device__ __forceinline__ void async16(const unsigned short* g, unsigned short* l) {
  __builtin_amdgcn_global_load_lds(
      (const __attribute__((address_space(1))) unsigned int*)g,
      (__attribute__((address_space(3))) unsigned int*)l, 16, 0, 0);
}

// Convert x (16384 blocks) + 4 weights (1024 blocks each) fp32 -> bf16.
__global__ __launch_bounds__(256) void cvt_all_kernel(
    const float* __restrict__ x,
    const float* __restrict__ w0, const float* __restrict__ w1,
    const float* __restrict__ w2, const float* __restrict__ w3,
    unsigned short* __restrict__ dx,
    unsigned short* __restrict__ d0, unsigned short* __restrict__ d1,
    unsigned short* __restrict__ d2, unsigned short* __restrict__ d3)
{
  const int b = blockIdx.x;
  const float* src; unsigned short* dst; long i;
  if (b < 16384) {
    src = x; dst = dx; i = (long)b * 256 + threadIdx.x;
  } else {
    const int r = b - 16384;
    const int s = r >> 10;
    src = s == 0 ? w0 : s == 1 ? w1 : s == 2 ? w2 : w3;
    dst = s == 0 ? d0 : s == 1 ? d1 : s == 2 ? d2 : d3;
    i = (long)(r & 1023) * 256 + threadIdx.x;
  }
  const float4 v = ((const float4*)src)[i];
  ushort4 o;
  o.x = f2bf(v.x); o.y = f2bf(v.y); o.z = f2bf(v.z); o.w = f2bf(v.w);
  ((ushort4*)dst)[i] = o;
}

// dst[k*1024+e] = bf16(src[e*1024+k]) for two matrices (z selects).
__global__ __launch_bounds__(256) void transpose_cvt_kernel(
    const float* __restrict__ s0, const float* __restrict__ s1,
    unsigned short* __restrict__ q0, unsigned short* __restrict__ q1)
{
  __shared__ unsigned short tile[64][66];
  const float* src = blockIdx.z ? s1 : s0;
  unsigned short* dst = blockIdx.z ? q1 : q0;
  const int e0 = blockIdx.y * 64;
  const int k0 = blockIdx.x * 64;
  const int t  = threadIdx.x;
  const int tr = t >> 4;        // 0..15
  const int tc = t & 15;        // 0..15
#pragma unroll
  for (int p = 0; p < 4; ++p) {
    const int el = p * 16 + tr;
    const float4 v = *(const float4*)&src[(long)(e0 + el) * DIMD + k0 + tc * 4];
    tile[el][tc * 4 + 0] = f2bf(v.x);
    tile[el][tc * 4 + 1] = f2bf(v.y);
    tile[el][tc * 4 + 2] = f2bf(v.z);
    tile[el][tc * 4 + 3] = f2bf(v.w);
  }
  __syncthreads();
#pragma unroll
  for (int p = 0; p < 4; ++p) {
    const int kl = p * 16 + tr;
    ushort4 o;
    o.x = tile[tc * 4 + 0][kl];
    o.y = tile[tc * 4 + 1][kl];
    o.z = tile[tc * 4 + 2][kl];
    o.w = tile[tc * 4 + 3][kl];
    *(ushort4*)&dst[(long)(k0 + kl) * DIMD + e0 + tc * 4] = o;
  }
}

// bkq[n] = sum_e Wkp[n,e]*bk[e] + bkp[n]; same for q-pair. 512 blocks x 4 waves.
__global__ __launch_bounds__(256) void bias_comb_kernel(
    const float* __restrict__ Wkp, const float* __restrict__ bk,
    const float* __restrict__ bkp,
    const float* __restrict__ Wqp, const float* __restrict__ bq,
    const float* __restrict__ bqp,
    float* __restrict__ bkq, float* __restrict__ bqq)
{
  const int b = blockIdx.x;
  const int which = b >> 8;
  const int lane = threadIdx.x & 63;
  const int wid  = threadIdx.x >> 6;
  const int n = (b & 255) * 4 + wid;
  const float* W    = which ? Wqp : Wkp;
  const float* bvec = which ? bq  : bk;
  const float* badd = which ? bqp : bkp;
  float*       outp = which ? bqq : bkq;
  float s = 0.f;
#pragma unroll
  for (int i = 0; i < 16; ++i)
    s += W[(long)n * DIMD + lane + i * 64] * bvec[lane + i * 64];
#pragma unroll
  for (int o = 32; o > 0; o >>= 1) s += __shfl_xor(s, o, 64);
  if (lane == 0) outp[n] = s + badd[n];
}

// ---------------------------------------------------------------------------
// 128^2 tile kernel — kept ONLY for the small weight-combine GEMM (MODE 1):
// C = A[M,1024] @ W[1024,1024]^T, z selects (A0/W0->O0, A1/W1->O1), bf16 out.
// ---------------------------------------------------------------------------
template <int MODE>
__global__ __launch_bounds__(256) void gemm_bt_kernel(
    const unsigned short* __restrict__ A0, const unsigned short* __restrict__ A1,
    const unsigned short* __restrict__ W0, const unsigned short* __restrict__ W1,
    const unsigned short* __restrict__ W2,
    const float* __restrict__ b0, const float* __restrict__ b1,
    const float* __restrict__ b2,
    const float* __restrict__ aux,
    unsigned short* __restrict__ O0, unsigned short* __restrict__ O1,
    unsigned short* __restrict__ O2,
    float* __restrict__ Of, const float* __restrict__ resid)
{
  __shared__ unsigned short lsA[TM * BK];
  __shared__ unsigned short lsB[TN * BK];

  const int tid  = threadIdx.x;
  const int lane = tid & 63;
  const int wid  = tid >> 6;
  const long bm  = (long)blockIdx.y * TM;
  const long bng = (long)blockIdx.x * TN;

  const unsigned short* A = A0;
  const unsigned short* W = W0;
  const float* bias = b0;
  unsigned short* Ob = O0;
  long bn = bng;
  int seg = 0;
  if (MODE == 0) {
    seg = (int)(bng >> 10);
    bn = bng & 1023;
    W    = seg == 0 ? W0 : (seg == 1 ? W1 : W2);
    bias = seg == 0 ? b0 : (seg == 1 ? b1 : b2);
    Ob   = seg == 0 ? O0 : (seg == 1 ? O1 : O2);
  } else if (MODE == 1) {
    if (blockIdx.z) { A = A1; W = W1; Ob = O1; }
  }

  const int wm = (wid & 1) * 64;
  const int wn = (wid >> 1) * 64;

  floatx4 acc[4][4];
#pragma unroll
  for (int i = 0; i < 4; ++i)
#pragma unroll
    for (int j = 0; j < 4; ++j)
      acc[i][j] = (floatx4)(0.0f);

  const int srow  = lane >> 3;
  const int pcol  = (lane & 7) * 8;
  const int lcolL = (((lane & 7) ^ (srow & 7)) * 8);
  const int frm   = lane & 15;
  const int cfrk  = lane >> 4;

  for (int kk = 0; kk < DIMD; kk += BK) {
    __syncthreads();
#pragma unroll
    for (int j = 0; j < 4; ++j) {
      const int inst = wid * 4 + j;
      const int r = inst * 8 + srow;
      async16(A + (bm + r) * (long)DIMD + kk + lcolL, &lsA[r * BK + pcol]);
      async16(W + (bn + r) * (long)DIMD + kk + lcolL, &lsB[r * BK + pcol]);
    }
    __syncthreads();
#pragma unroll
    for (int ks = 0; ks < BK; ks += 32) {
      const int cb  = (ks >> 3) + cfrk;
      const int swz = ((cb ^ (frm & 7)) << 3);
      bf16x8 af[4], bfr[4];
#pragma unroll
      for (int i = 0; i < 4; ++i)
        af[i]  = *(const bf16x8*)&lsA[(wm + i * 16 + frm) * BK + swz];
#pragma unroll
      for (int i = 0; i < 4; ++i)
        bfr[i] = *(const bf16x8*)&lsB[(wn + i * 16 + frm) * BK + swz];
#pragma unroll
      for (int i = 0; i < 4; ++i)
#pragma unroll
        for (int j = 0; j < 4; ++j)
          acc[i][j] = __builtin_amdgcn_mfma_f32_16x16x32_bf16(af[i], bfr[j], acc[i][j], 0, 0, 0);
    }
  }

  const int cn = lane & 15;
  const int rq = (lane >> 4) * 4;
#pragma unroll
  for (int j = 0; j < 4; ++j) {
    const long col = bn + wn + j * 16 + cn;
    const float bv = (MODE == 1) ? 0.0f : bias[col];
    const float pv = (MODE == 0) ? aux[col] : 0.0f;
#pragma unroll
    for (int i = 0; i < 4; ++i) {
#pragma unroll
      for (int r = 0; r < 4; ++r) {
        const long row = bm + wm + i * 16 + rq + r;
        const float v = acc[i][j][r] + bv;
        if (MODE == 0) {
          Ob[row * (long)DIMD + col] = (seg == 0) ? f2bf(v)
                                                  : f2bf(tanh_fast(v) * pv);
        } else if (MODE == 1) {
          Ob[row * (long)DIMD + col] = f2bf(v);
        } else {
          Of[row * (long)DIMD + col] = v + resid[row * (long)DIMD + col];
        }
      }
    }
  }
}

// ---------------------------------------------------------------------------
// 256^2-tile, 8-wave, double-buffered, phase-interleaved GEMM (T2+T3+T4+T5).
// C = A[M,1024] @ W[1024,1024]^T.
//   MODE 0: fused interior (3 N-segments: V | tanh*ph | tanh*ph), bf16 out.
//           NOTE: phase outputs (segs 1,2) are scaled by 1/(2*pi) — the scan
//           kernel consumes them as REVOLUTIONS via native v_sin/v_cos.
//   MODE 2: final: f32 out = acc + bias + resid.
// Schedule per K-tile T (buf c, staging buf n), ONLY 2 barriers per tile:
//   P0: rd c.h0(A0)+B(h0); stage A-h0(T+1)->n;                      16 MFMA
//   P1: rd c.h0(A1);       stage B-h0(T+1)->n; vmcnt(4); BAR;       16 MFMA
//   P2: rd c.h1(A0)+B(h1); stage A-h1(T+1)->n;                      16 MFMA
//   P3: rd c.h1(A1);       stage B-h1(T+1)->n; vmcnt(4); BAR;       16 MFMA
// RAW: reads of half h are issued after the barrier following the vmcnt(4)
//   that forced h's 4 loads; vmcnt(4) with 8 outstanding forces the oldest 4.
// WAR: stage into buf n half h is >=1 barrier after the last reads of n.h,
//   and each reader's lgkm-wait-before-MFMA completes its reads before it
//   can reach that barrier (m201-template safety argument).
// LDS: [A0|A1|B0|B1] x 16K shorts = 128 KiB -> 1 block/CU, 8 waves.
// Swizzle: 16B slot ^ ((row>>1)&3) within 64B rows; pre-swizzled global src +
// swizzled ds_read (both-sides involution) -> 0 bank conflicts (measured).
// Epilogue: row-major store order (j innermost) -> full-sector writes
// (WRITE_SIZE == logical 96 MiB, measured).
// ---------------------------------------------------------------------------
#define TILE16 16384   // shorts per 256x64 tile buffer
#define HALF16 8192    // shorts per k-half (256 rows x 32 cols)

template <int MODE>
__global__ __launch_bounds__(512, 2) void gemm256_kernel(
    const unsigned short* __restrict__ A,
    const unsigned short* __restrict__ W0, const unsigned short* __restrict__ W1,
    const unsigned short* __restrict__ W2,
    const float* __restrict__ b0, const float* __restrict__ b1,
    const float* __restrict__ b2,
    const float* __restrict__ aux,
    unsigned short* __restrict__ O0, unsigned short* __restrict__ O1,
    unsigned short* __restrict__ O2,
    float* __restrict__ Of, const float* __restrict__ resid)
{
  __shared__ unsigned short lds[4 * TILE16];  // 128 KiB

  const int tid  = threadIdx.x;
  const int lane = tid & 63;
  const int wid  = tid >> 6;

  // XCD-bijective block swizzle (nwg % 8 == 0 for both modes).
  constexpr int NBX = (MODE == 0) ? 12 : 4;
  constexpr int NWG = NBX * 64;
  const int orig = blockIdx.x + blockIdx.y * gridDim.x;
  const int swzb = (orig & 7) * (NWG >> 3) + (orig >> 3);
  const int nb = swzb % NBX;
  const int mb = swzb / NBX;

  const long bm = (long)mb * 256;
  long bn;
  int seg = 0;
  const unsigned short* W = W0;
  const float* bias = b0;
  unsigned short* Ob = O0;
  if (MODE == 0) {
    seg = nb >> 2;
    bn  = (long)(nb & 3) * 256;
    W    = seg == 0 ? W0 : (seg == 1 ? W1 : W2);
    bias = seg == 0 ? b0 : (seg == 1 ? b1 : b2);
    Ob   = seg == 0 ? O0 : (seg == 1 ? O1 : O2);
  } else {
    bn = (long)nb * 256;
  }

  const int wm = (wid >> 2) * 128;   // 2 row-halves of waves
  const int wn = (wid & 3) * 64;     // 4 col-quarters of waves

  // ---- staging constants: wave wid stages row-groups q0,q0+1 (16 rows each)
  const int q0  = wid * 2;
  const int sr0 = q0 * 16 + (lane >> 2);                  // row (j=0); j=1 is +16
  const int sg  = (((lane & 3) ^ ((sr0 >> 1) & 3)) * 8);  // pre-swizzled src col
  const int sd0 = q0 * 512 + lane * 8;                    // linear LDS dest
  const long arow = (bm + sr0) * (long)DIMD;
  const long brow = (bn + sr0) * (long)DIMD;

  // ---- read constants (ds_read_b128 fragment addressing, swizzled slot)
  const int frm   = lane & 15;
  const int cfrk  = lane >> 4;
  const int slot8 = (cfrk ^ ((frm >> 1) & 3)) * 8;
  const int rbase = frm * 32 + slot8;

  floatx4 acc[8][4];
#pragma unroll
  for (int i = 0; i < 8; ++i)
#pragma unroll
    for (int j = 0; j < 4; ++j) acc[i][j] = (floatx4)(0.0f);

  bf16x8 bfr[4];

#define SA256(buf, kk, h) do { \
    const unsigned short* _s = A + arow + (kk) + (h) * 32 + sg; \
    unsigned short* _d = &lds[(buf) * TILE16 + (h) * HALF16 + sd0]; \
    async16(_s, _d); \
    async16(_s + 16 * DIMD, _d + 512); \
  } while (0)
#define SB256(buf, kk, h) do { \
    const unsigned short* _s = W + brow + (kk) + (h) * 32 + sg; \
    unsigned short* _d = &lds[2 * TILE16 + (buf) * TILE16 + (h) * HALF16 + sd0]; \
    async16(_s, _d); \
    async16(_s + 16 * DIMD, _d + 512); \
  } while (0)
#define RDA256(buf, h, ih, af) do { \
    const int _ab = (buf) * TILE16 + (h) * HALF16 + (wm + (ih) * 64) * 32 + rbase; \
    _Pragma("unroll") \
    for (int _i = 0; _i < 4; ++_i) (af)[_i] = *(const bf16x8*)&lds[_ab + _i * 512]; \
  } while (0)
#define RDB256(buf, h) do { \
    const int _bb = 2 * TILE16 + (buf) * TILE16 + (h) * HALF16 + wn * 32 + rbase; \
    _Pragma("unroll") \
    for (int _j = 0; _j < 4; ++_j) bfr[_j] = *(const bf16x8*)&lds[_bb + _j * 512]; \
  } while (0)
#define VMW4() asm volatile("s_waitcnt vmcnt(4)" ::: "memory")
#define BAR256() do { \
    asm volatile("" ::: "memory"); \
    __builtin_amdgcn_s_barrier(); \
    asm volatile("" ::: "memory"); \
  } while (0)
#define MFMA16(ih, af) do { \
    __builtin_amdgcn_s_setprio(1); \
    _Pragma("unroll") \
    for (int _i = 0; _i < 4; ++_i) \
      _Pragma("unroll") \
      for (int _j = 0; _j < 4; ++_j) \
        acc[(ih) * 4 + _i][_j] = __builtin_amdgcn_mfma_f32_16x16x32_bf16( \
            (af)[_i], bfr[_j], acc[(ih) * 4 + _i][_j], 0, 0, 0); \
    __builtin_amdgcn_s_setprio(0); \
  } while (0)
// One K-tile: compute buf c, stage next tile (cols kn) into buf n.
#define KTILE(c, n, kn) do { \
    { bf16x8 af[4]; RDA256(c, 0, 0, af); RDB256(c, 0); \
      SA256(n, kn, 0); MFMA16(0, af); } \
    { bf16x8 af[4]; RDA256(c, 0, 1, af); \
      SB256(n, kn, 0); VMW4(); BAR256(); MFMA16(1, af); } \
    { bf16x8 af[4]; RDA256(c, 1, 0, af); RDB256(c, 1); \
      SA256(n, kn, 1); MFMA16(0, af); } \
    { bf16x8 af[4]; RDA256(c, 1, 1, af); \
      SB256(n, kn, 1); VMW4(); BAR256(); MFMA16(1, af); } \
  } while (0)

  // prologue: stage tile 0 (8 loads), force its h0 halves, sync.
  SA256(0, 0, 0); SB256(0, 0, 0); SA256(0, 0, 1); SB256(0, 0, 1);
  VMW4();
  BAR256();

#pragma unroll 1
  for (int t = 0; t < 16; t += 2) {
    const int k1 = (t + 1) * 64;
    const int k2 = (t + 2 < 16) ? (t + 2) * 64 : 0;  // dummy restage keeps vmcnt uniform
    KTILE(0, 1, k1);
    KTILE(1, 0, k2);
  }
  // drain the dummy stages before LDS dealloc at endpgm
  asm volatile("s_waitcnt vmcnt(0)" ::: "memory");

#undef SA256
#undef SB256
#undef RDA256
#undef RDB256
#undef VMW4
#undef BAR256
#undef MFMA16
#undef KTILE

  // ---- epilogue: row-major store order, j innermost for full-sector writes.
  const int cn = lane & 15;
  const int rq = (lane >> 4) * 4;
  long colj[4]; float bvj[4], pvj[4];
#pragma unroll
  for (int j = 0; j < 4; ++j) {
    colj[j] = bn + wn + j * 16 + cn;
    bvj[j]  = bias[colj[j]];
    // Phases stored in revolutions: fold 1/(2*pi) into the phase scale.
    pvj[j]  = (MODE == 0) ? aux[colj[j]] * INV2PI : 0.0f;
  }
#pragma unroll
  for (int ii = 0; ii < 8; ++ii) {
#pragma unroll
    for (int r = 0; r < 4; ++r) {
      const long rowo = (bm + wm + ii * 16 + rq + r) * (long)DIMD;
#pragma unroll
      for (int j = 0; j < 4; ++j) {
        const float v = acc[ii][j][r] + bvj[j];
        if (MODE == 0) {
          Ob[rowo + colj[j]] = (seg == 0) ? f2bf(v)
                                          : f2bf(tanh_fast(v) * pvj[j]);
        } else {
          Of[rowo + colj[j]] = v + resid[rowo + colj[j]];
        }
      }
    }
  }
}

// One block per chunk, 512 threads x 2 dims (8 waves/block -> 2 waves/SIMD).
// Phases arrive in REVOLUTIONS (scaled by 1/2pi in gemm256 MODE 0), so
// sin/cos are single native v_sin_f32/v_cos_f32 ops (|x|<=0.5 in-domain).
// Scan loop: groups of 8 t-steps, register double-buffered — group g+1's 24
// ushort2 loads issue before group g's compute (prefetch also crosses the
// LN-phase barriers), hiding HBM latency under ~8 steps of VALU.
__global__ __launch_bounds__(512) void scan_ln_kernel(
    const unsigned short* __restrict__ V,  const unsigned short* __restrict__ KP,
    const unsigned short* __restrict__ QP,
    const float* __restrict__ lng, const float* __restrict__ lnb,
    unsigned short* __restrict__ out)
{
  __shared__ unsigned short ret_s[32][DIMD];   // 64 KB

  const int tid  = threadIdx.x;
  const int lane = tid & 63;
  const int wid  = tid >> 6;          // 0..7
  const long rowBase = (long)blockIdx.x * CHUNKLEN;
  const int d0 = tid * 2;

  const int c0 = lane * 8;
  const int c1 = 512 + lane * 8;
  float g0[8], be0[8], g1[8], be1[8];
#pragma unroll
  for (int j = 0; j < 8; ++j) {
    g0[j] = lng[c0 + j]; be0[j] = lnb[c0 + j];
    g1[j] = lng[c1 + j]; be1[j] = lnb[c1 + j];
  }

  float mr[2] = {0.f, 0.f};
  float mi[2] = {0.f, 0.f};

  ushort2 aV[8], aK[8], aQ[8];   // buffer A
  ushort2 bV[8], bK[8], bQ[8];   // buffer B

#define LOADG(BV, BK_, BQ, t8) do { \
    _Pragma("unroll") \
    for (int _u = 0; _u < 8; ++_u) { \
      const long _o = (rowBase + (t8) + _u) * DIMD + d0; \
      BV[_u]  = *(const ushort2*)(V  + _o); \
      BK_[_u] = *(const ushort2*)(KP + _o); \
      BQ[_u]  = *(const ushort2*)(QP + _o); \
    } \
  } while (0)
#define COMP8(BV, BK_, BQ, lr0) do { \
    _Pragma("unroll") \
    for (int _u = 0; _u < 8; ++_u) { \
      const unsigned short _va[2] = {BV[_u].x, BV[_u].y}; \
      const unsigned short _ka[2] = {BK_[_u].x, BK_[_u].y}; \
      const unsigned short _qa[2] = {BQ[_u].x, BQ[_u].y}; \
      unsigned short _rv[2]; \
      _Pragma("unroll") \
      for (int _j = 0; _j < 2; ++_j) { \
        const float _v  = bf2f(_va[_j]); \
        const float _kp = bf2f(_ka[_j]); \
        const float _qp = bf2f(_qa[_j]); \
        const float _skp = __builtin_amdgcn_sinf(_kp); \
        const float _ckp = __builtin_amdgcn_cosf(_kp); \
        const float _sqp = __builtin_amdgcn_sinf(_qp); \
        const float _cqp = __builtin_amdgcn_cosf(_qp); \
        mr[_j] += _v * _ckp; \
        mi[_j] += _v * _skp; \
        _rv[_j] = f2bf((mr[_j] * _cqp + mi[_j] * _sqp) * 0.03125f); \
      } \
      ushort2 _o2; _o2.x = _rv[0]; _o2.y = _rv[1]; \
      *(ushort2*)&ret_s[(lr0) + _u][d0] = _o2; \
    } \
  } while (0)
#define LNPH2(hb) do { \
    _Pragma("unroll 1") \
    for (int rr = 0; rr < 4; ++rr) { \
      const int tl = wid * 4 + rr; \
      const ushort8v a0 = *(const ushort8v*)&ret_s[tl][c0]; \
      const ushort8v a1 = *(const ushort8v*)&ret_s[tl][c1]; \
      float f0[8], f1[8]; \
      float s = 0.f, s2 = 0.f; \
      _Pragma("unroll") \
      for (int j = 0; j < 8; ++j) { \
        f0[j] = bf2f(a0[j]); f1[j] = bf2f(a1[j]); \
        s += f0[j] + f1[j]; \
        s2 += f0[j] * f0[j] + f1[j] * f1[j]; \
      } \
      _Pragma("unroll") \
      for (int o = 32; o > 0; o >>= 1) { \
        s  += __shfl_xor(s,  o, 64); \
        s2 += __shfl_xor(s2, o, 64); \
      } \
      const float mu  = s * (1.0f / DIMD); \
      const float var = s2 * (1.0f / DIMD) - mu * mu; \
      const float inv = rsqrtf(var + 1e-5f); \
      ushort8v o0, o1; \
      _Pragma("unroll") \
      for (int j = 0; j < 8; ++j) { \
        o0[j] = f2bf((f0[j] - mu) * inv * g0[j] + be0[j]); \
        o1[j] = f2bf((f1[j] - mu) * inv * g1[j] + be1[j]); \
      } \
      const long gro = (rowBase + (hb) + tl) * DIMD; \
      *(ushort8v*)(out + gro + c0) = o0; \
      *(ushort8v*)(out + gro + c1) = o1; \
    } \
  } while (0)

  // ---- h = 0 ----
  LOADG(aV, aK, aQ, 0);
  LOADG(bV, bK, bQ, 8);  COMP8(aV, aK, aQ, 0);
  LOADG(aV, aK, aQ, 16); COMP8(bV, bK, bQ, 8);
  LOADG(bV, bK, bQ, 24); COMP8(aV, aK, aQ, 16);
  LOADG(aV, aK, aQ, 32); COMP8(bV, bK, bQ, 24);   // prefetch h1-g0 across barrier
  __syncthreads();
  LNPH2(0);
  __syncthreads();
  // ---- h = 1 ----
  LOADG(bV, bK, bQ, 40); COMP8(aV, aK, aQ, 0);
  LOADG(aV, aK, aQ, 48); COMP8(bV, bK, bQ, 8);
  LOADG(bV, bK, bQ, 56); COMP8(aV, aK, aQ, 16);
                         COMP8(bV, bK, bQ, 24);
  __syncthreads();
  LNPH2(32);
  __syncthreads();

#undef LOADG
#undef COMP8
#undef LNPH2
}

extern "C" void kernel_launch(void* const* d_in, const int* in_sizes, int n_in,
                              void* d_out, int out_size, void* d_ws, size_t ws_size,
                              hipStream_t stream)
{
  const float* x   = (const float*)d_in[0];
  const float* Wk  = (const float*)d_in[1];
  const float* bk  = (const float*)d_in[2];
  const float* Wv  = (const float*)d_in[3];
  const float* bv  = (const float*)d_in[4];
  const float* Wq  = (const float*)d_in[5];
  const float* bq  = (const float*)d_in[6];
  const float* Wkp = (const float*)d_in[7];
  const float* bkp = (const float*)d_in[8];
  const float* Wqp = (const float*)d_in[9];
  const float* bqp = (const float*)d_in[10];
  const float* ph  = (const float*)d_in[11];
  const float* lng = (const float*)d_in[12];
  const float* lnb = (const float*)d_in[13];
  const float* Wo  = (const float*)d_in[14];
  const float* bo  = (const float*)d_in[15];
  float* out = (float*)d_out;

  const long NB = (long)NTOK * DIMD;
  const long DD = (long)DIMD * DIMD;
  const size_t required = (size_t)(4 * NB + 8 * DD) * sizeof(unsigned short)
                        + 2048 * sizeof(float);
  if (ws_size < required) return;

  unsigned short* S0   = (unsigned short*)d_ws;  // xb, later Rln
  unsigned short* SV   = S0   + NB;
  unsigned short* SKP  = SV   + NB;
  unsigned short* SQP  = SKP  + NB;
  unsigned short* Wvb  = SQP  + NB;
  unsigned short* Wob  = Wvb  + DD;
  unsigned short* Wkpb = Wob  + DD;
  unsigned short* Wqpb = Wkpb + DD;
  unsigned short* WkT  = Wqpb + DD;
  unsigned short* WqT  = WkT  + DD;
  unsigned short* Wkqb = WqT  + DD;
  unsigned short* Wqqb = Wkqb + DD;
  float* bkq = (float*)(Wqqb + DD);
  float* bqq = bkq + DIMD;

  dim3 blk(256);

  // 1) fp32->bf16: x, Wv, Wo, Wkp, Wqp
  cvt_all_kernel<<<dim3(16384 + 4 * 1024), blk, 0, stream>>>(
      x, Wv, Wo, Wkp, Wqp, S0, Wvb, Wob, Wkpb, Wqpb);
  // 2) WkT = Wk^T (bf16), WqT = Wq^T
  transpose_cvt_kernel<<<dim3(16, 16, 2), blk, 0, stream>>>(Wk, Wq, WkT, WqT);
  // 3) combined biases: bkq = Wkp@bk + bkp ; bqq = Wqp@bq + bqp
  bias_comb_kernel<<<dim3(512), blk, 0, stream>>>(Wkp, bk, bkp, Wqp, bq, bqp, bkq, bqq);
  // 4) combined weights: Wkq = Wkp@Wk ; Wqq likewise (small -> 128^2 kernel)
  gemm_bt_kernel<1><<<dim3(DIMD / TN, DIMD / TM, 2), blk, 0, stream>>>(
      Wkpb, Wqpb, WkT, WqT, nullptr, nullptr, nullptr, nullptr, nullptr,
      Wkqb, Wqqb, nullptr, nullptr, nullptr);
  // 5) fused interior: V | KP = tanh(x@Wkq^T+bkq)*ph/2pi | QP likewise
  gemm256_kernel<0><<<dim3(12, NTOK / 256), dim3(512), 0, stream>>>(
      S0, Wvb, Wkqb, Wqqb, bv, bkq, bqq, ph, SV, SKP, SQP, nullptr, nullptr);
  // 6) scan + layernorm -> Rln (reuses S0)
  scan_ln_kernel<<<dim3(NTOK / CHUNKLEN), dim3(512), 0, stream>>>(
      SV, SKP, SQP, lng, lnb, S0);
  // 7) out = Rln@Wo^T + bo + x  (fp32)
  gemm256_kernel<2><<<dim3(4, NTOK / 256), dim3(512), 0, stream>>>(
      S0, Wob, nullptr, nullptr, bo, nullptr, nullptr, nullptr,
      nullptr, nullptr, nullptr, out, x);
}

// Round 5
// 354.296 us; speedup vs baseline: 1.0306x; 1.0306x over previous
//
#include <hip/hip_runtime.h>
#include <math.h>

#define DIMD 1024
#define CHUNKLEN 64
#define NTOK 16384   // B*S = 4*4096

#define TM 128
#define TN 128
#define BK 64

#define INV2PI 0.15915494309189535f

typedef __bf16 bf16x8 __attribute__((ext_vector_type(8)));
typedef float floatx4 __attribute__((ext_vector_type(4)));
typedef unsigned short ushort8v __attribute__((ext_vector_type(8)));

__device__ __forceinline__ float bf2f(unsigned short u) {
  union { unsigned int i; float f; } v; v.i = ((unsigned int)u) << 16; return v.f;
}
__device__ __forceinline__ unsigned short f2bf(float f) {
  union { float f; unsigned int i; } v; v.f = f;
  unsigned int r = v.i + 0x7FFFu + ((v.i >> 16) & 1u);
  return (unsigned short)(r >> 16);
}

// tanh(v) = 1 - 2/(e^{2v}+1); exp->inf gives 1, exp->0 gives -1 (no NaN).
__device__ __forceinline__ float tanh_fast(float v) {
  const float t = __expf(2.0f * v);
  return 1.0f - 2.0f * __builtin_amdgcn_rcpf(t + 1.0f);
}

__device__ __forceinline__ void async16(const unsigned short* g, unsigned short* l) {
  __builtin_amdgcn_global_load_lds(
      (const __attribute__((address_space(1))) unsigned int*)g,
      (__attribute__((address_space(3))) unsigned int*)l, 16, 0, 0);
}

// ---------------------------------------------------------------------------
// Fused prep kernel (one launch):
//   blocks [0, 20480)        : fp32->bf16 cvt of x + 4 weights
//   blocks [20480, 20992)    : transpose-cvt of Wk, Wq
//   blocks [20992, 21504)    : combined-bias dot products
// ---------------------------------------------------------------------------
__global__ __launch_bounds__(256) void prep_kernel(
    const float* __restrict__ x,
    const float* __restrict__ w0, const float* __restrict__ w1,
    const float* __restrict__ w2, const float* __restrict__ w3,
    unsigned short* __restrict__ dx,
    unsigned short* __restrict__ d0, unsigned short* __restrict__ d1,
    unsigned short* __restrict__ d2, unsigned short* __restrict__ d3,
    const float* __restrict__ Wk, const float* __restrict__ Wq,
    unsigned short* __restrict__ WkT, unsigned short* __restrict__ WqT,
    const float* __restrict__ bk, const float* __restrict__ bkp,
    const float* __restrict__ bq, const float* __restrict__ bqp,
    float* __restrict__ bkq, float* __restrict__ bqq)
{
  const int b = blockIdx.x;
  if (b < 20480) {
    // ---- cvt ----
    const float* src; unsigned short* dst; long i;
    if (b < 16384) {
      src = x; dst = dx; i = (long)b * 256 + threadIdx.x;
    } else {
      const int r = b - 16384;
      const int s = r >> 10;
      src = s == 0 ? w0 : s == 1 ? w1 : s == 2 ? w2 : w3;
      dst = s == 0 ? d0 : s == 1 ? d1 : s == 2 ? d2 : d3;
      i = (long)(r & 1023) * 256 + threadIdx.x;
    }
    const float4 v = ((const float4*)src)[i];
    ushort4 o;
    o.x = f2bf(v.x); o.y = f2bf(v.y); o.z = f2bf(v.z); o.w = f2bf(v.w);
    ((ushort4*)dst)[i] = o;
  } else if (b < 20992) {
    // ---- transpose-cvt: dst[k*1024+e] = bf16(src[e*1024+k]) ----
    __shared__ unsigned short tile[64][66];
    const int r2 = b - 20480;
    const int z  = r2 >> 8;
    const int rem = r2 & 255;
    const float* src = z ? Wq : Wk;
    unsigned short* dst = z ? WqT : WkT;
    const int k0 = (rem & 15) * 64;
    const int e0 = (rem >> 4) * 64;
    const int t  = threadIdx.x;
    const int tr = t >> 4;        // 0..15
    const int tc = t & 15;        // 0..15
#pragma unroll
    for (int p = 0; p < 4; ++p) {
      const int el = p * 16 + tr;
      const float4 v = *(const float4*)&src[(long)(e0 + el) * DIMD + k0 + tc * 4];
      tile[el][tc * 4 + 0] = f2bf(v.x);
      tile[el][tc * 4 + 1] = f2bf(v.y);
      tile[el][tc * 4 + 2] = f2bf(v.z);
      tile[el][tc * 4 + 3] = f2bf(v.w);
    }
    __syncthreads();
#pragma unroll
    for (int p = 0; p < 4; ++p) {
      const int kl = p * 16 + tr;
      ushort4 o;
      o.x = tile[tc * 4 + 0][kl];
      o.y = tile[tc * 4 + 1][kl];
      o.z = tile[tc * 4 + 2][kl];
      o.w = tile[tc * 4 + 3][kl];
      *(ushort4*)&dst[(long)(k0 + kl) * DIMD + e0 + tc * 4] = o;
    }
  } else {
    // ---- combined biases: bkq[n] = Wkp@bk + bkp ; bqq[n] = Wqp@bq + bqp ----
    const int r3 = b - 20992;           // 0..511
    const int which = r3 >> 8;
    const int lane = threadIdx.x & 63;
    const int wid  = threadIdx.x >> 6;
    const int n = (r3 & 255) * 4 + wid;
    const float* W    = which ? w3 : w2;   // w2 = Wkp (f32), w3 = Wqp (f32)
    const float* bvec = which ? bq  : bk;
    const float* badd = which ? bqp : bkp;
    float*       outp = which ? bqq : bkq;
    float s = 0.f;
#pragma unroll
    for (int i = 0; i < 16; ++i)
      s += W[(long)n * DIMD + lane + i * 64] * bvec[lane + i * 64];
#pragma unroll
    for (int o = 32; o > 0; o >>= 1) s += __shfl_xor(s, o, 64);
    if (lane == 0) outp[n] = s + badd[n];
  }
}

// ---------------------------------------------------------------------------
// 128^2 tile kernel — kept ONLY for the small weight-combine GEMM (MODE 1):
// C = A[M,1024] @ W[1024,1024]^T, z selects (A0/W0->O0, A1/W1->O1), bf16 out.
// ---------------------------------------------------------------------------
template <int MODE>
__global__ __launch_bounds__(256) void gemm_bt_kernel(
    const unsigned short* __restrict__ A0, const unsigned short* __restrict__ A1,
    const unsigned short* __restrict__ W0, const unsigned short* __restrict__ W1,
    unsigned short* __restrict__ O0, unsigned short* __restrict__ O1)
{
  __shared__ unsigned short lsA[TM * BK];
  __shared__ unsigned short lsB[TN * BK];

  const int tid  = threadIdx.x;
  const int lane = tid & 63;
  const int wid  = tid >> 6;
  const long bm  = (long)blockIdx.y * TM;
  const long bn  = (long)blockIdx.x * TN;

  const unsigned short* A = A0;
  const unsigned short* W = W0;
  unsigned short* Ob = O0;
  if (blockIdx.z) { A = A1; W = W1; Ob = O1; }

  const int wm = (wid & 1) * 64;
  const int wn = (wid >> 1) * 64;

  floatx4 acc[4][4];
#pragma unroll
  for (int i = 0; i < 4; ++i)
#pragma unroll
    for (int j = 0; j < 4; ++j)
      acc[i][j] = (floatx4)(0.0f);

  const int srow  = lane >> 3;
  const int pcol  = (lane & 7) * 8;
  const int lcolL = (((lane & 7) ^ (srow & 7)) * 8);
  const int frm   = lane & 15;
  const int cfrk  = lane >> 4;

  for (int kk = 0; kk < DIMD; kk += BK) {
    __syncthreads();
#pragma unroll
    for (int j = 0; j < 4; ++j) {
      const int inst = wid * 4 + j;
      const int r = inst * 8 + srow;
      async16(A + (bm + r) * (long)DIMD + kk + lcolL, &lsA[r * BK + pcol]);
      async16(W + (bn + r) * (long)DIMD + kk + lcolL, &lsB[r * BK + pcol]);
    }
    __syncthreads();
#pragma unroll
    for (int ks = 0; ks < BK; ks += 32) {
      const int cb  = (ks >> 3) + cfrk;
      const int swz = ((cb ^ (frm & 7)) << 3);
      bf16x8 af[4], bfr[4];
#pragma unroll
      for (int i = 0; i < 4; ++i)
        af[i]  = *(const bf16x8*)&lsA[(wm + i * 16 + frm) * BK + swz];
#pragma unroll
      for (int i = 0; i < 4; ++i)
        bfr[i] = *(const bf16x8*)&lsB[(wn + i * 16 + frm) * BK + swz];
#pragma unroll
      for (int i = 0; i < 4; ++i)
#pragma unroll
        for (int j = 0; j < 4; ++j)
          acc[i][j] = __builtin_amdgcn_mfma_f32_16x16x32_bf16(af[i], bfr[j], acc[i][j], 0, 0, 0);
    }
  }

  const int cn = lane & 15;
  const int rq = (lane >> 4) * 4;
#pragma unroll
  for (int j = 0; j < 4; ++j) {
    const long col = bn + wn + j * 16 + cn;
#pragma unroll
    for (int i = 0; i < 4; ++i) {
#pragma unroll
      for (int r = 0; r < 4; ++r) {
        const long row = bm + wm + i * 16 + rq + r;
        Ob[row * (long)DIMD + col] = f2bf(acc[i][j][r]);
      }
    }
  }
}

// ---------------------------------------------------------------------------
// 256^2-tile, 8-wave, double-buffered, phase-interleaved GEMM (T2+T3+T4+T5).
// C = A[M,1024] @ W[1024,1024]^T.
//   MODE 0: V segment only: bf16 = acc + bias.             grid (4, 64)
//   MODE 3: phase segments: bf16 = tanh(acc+bias)*aux/2pi. grid (8, 64)
//   MODE 2: final: f32 out = acc + bias + resid.           grid (4, 64)
// (MODE 0/3 split keeps each dispatch an exact multiple of the 256-CU batch
//  width — performance-neutral vs fused, but attributable in the profile.)
// Schedule per K-tile T (buf c, staging buf n), 2 barriers per tile:
//   P0: rd c.h0(A0)+B(h0); stage A-h0(T+1)->n;                      16 MFMA
//   P1: rd c.h0(A1);       stage B-h0(T+1)->n; vmcnt(4); BAR;       16 MFMA
//   P2: rd c.h1(A0)+B(h1); stage A-h1(T+1)->n;                      16 MFMA
//   P3: rd c.h1(A1);       stage B-h1(T+1)->n; vmcnt(4); BAR;       16 MFMA
// RAW: reads of half h are issued after the barrier following the vmcnt(4)
//   that forced h's 4 loads; vmcnt(4) with 8 outstanding forces the oldest 4.
// WAR: stage into buf n half h is >=1 barrier after the last reads of n.h
//   (m201-template safety argument). vmcnt never drains <4 in the main loop.
// LDS: [A0|A1|B0|B1] x 16K shorts = 128 KiB -> 1 block/CU, 8 waves.
// Swizzle: 16B slot ^ ((row>>1)&3) within 64B rows; pre-swizzled global src +
// swizzled ds_read (both-sides involution) -> 0 bank conflicts (measured).
// Epilogue: row-major store order -> full-sector writes (measured).
// ---------------------------------------------------------------------------
#define TILE16 16384   // shorts per 256x64 tile buffer
#define HALF16 8192    // shorts per k-half (256 rows x 32 cols)

template <int MODE>
__global__ __launch_bounds__(512, 2) void gemm256_kernel(
    const unsigned short* __restrict__ A,
    const unsigned short* __restrict__ W0, const unsigned short* __restrict__ W1,
    const unsigned short* __restrict__ W2,
    const float* __restrict__ b0, const float* __restrict__ b1,
    const float* __restrict__ b2,
    const float* __restrict__ aux,
    unsigned short* __restrict__ O0, unsigned short* __restrict__ O1,
    unsigned short* __restrict__ O2,
    float* __restrict__ Of, const float* __restrict__ resid)
{
  __shared__ unsigned short lds[4 * TILE16];  // 128 KiB

  const int tid  = threadIdx.x;
  const int lane = tid & 63;
  const int wid  = tid >> 6;

  // XCD-bijective block swizzle (nwg % 8 == 0 for all modes).
  constexpr int NBX = (MODE == 3) ? 8 : 4;
  constexpr int NWG = NBX * 64;
  const int orig = blockIdx.x + blockIdx.y * gridDim.x;
  const int swzb = (orig & 7) * (NWG >> 3) + (orig >> 3);
  const int nb = swzb % NBX;
  const int mb = swzb / NBX;

  const long bm = (long)mb * 256;
  long bn;
  const unsigned short* W = W0;
  const float* bias = b0;
  unsigned short* Ob = O0;
  if (MODE == 3) {
    const int sl = nb >> 2;            // 0 -> K-phase, 1 -> Q-phase
    bn   = (long)(nb & 3) * 256;
    W    = sl ? W2 : W1;
    bias = sl ? b2 : b1;
    Ob   = sl ? O2 : O1;
  } else {
    bn = (long)nb * 256;
  }

  const int wm = (wid >> 2) * 128;   // 2 row-halves of waves
  const int wn = (wid & 3) * 64;     // 4 col-quarters of waves

  // ---- staging constants: wave wid stages row-groups q0,q0+1 (16 rows each)
  const int q0  = wid * 2;
  const int sr0 = q0 * 16 + (lane >> 2);                  // row (j=0); j=1 is +16
  const int sg  = (((lane & 3) ^ ((sr0 >> 1) & 3)) * 8);  // pre-swizzled src col
  const int sd0 = q0 * 512 + lane * 8;                    // linear LDS dest
  const long arow = (bm + sr0) * (long)DIMD;
  const long brow = (bn + sr0) * (long)DIMD;

  // ---- read constants (ds_read_b128 fragment addressing, swizzled slot)
  const int frm   = lane & 15;
  const int cfrk  = lane >> 4;
  const int slot8 = (cfrk ^ ((frm >> 1) & 3)) * 8;
  const int rbase = frm * 32 + slot8;

  floatx4 acc[8][4];
#pragma unroll
  for (int i = 0; i < 8; ++i)
#pragma unroll
    for (int j = 0; j < 4; ++j) acc[i][j] = (floatx4)(0.0f);

  bf16x8 bfr[4];

#define SA256(buf, kk, h) do { \
    const unsigned short* _s = A + arow + (kk) + (h) * 32 + sg; \
    unsigned short* _d = &lds[(buf) * TILE16 + (h) * HALF16 + sd0]; \
    async16(_s, _d); \
    async16(_s + 16 * DIMD, _d + 512); \
  } while (0)
#define SB256(buf, kk, h) do { \
    const unsigned short* _s = W + brow + (kk) + (h) * 32 + sg; \
    unsigned short* _d = &lds[2 * TILE16 + (buf) * TILE16 + (h) * HALF16 + sd0]; \
    async16(_s, _d); \
    async16(_s + 16 * DIMD, _d + 512); \
  } while (0)
#define RDA256(buf, h, ih, af) do { \
    const int _ab = (buf) * TILE16 + (h) * HALF16 + (wm + (ih) * 64) * 32 + rbase; \
    _Pragma("unroll") \
    for (int _i = 0; _i < 4; ++_i) (af)[_i] = *(const bf16x8*)&lds[_ab + _i * 512]; \
  } while (0)
#define RDB256(buf, h) do { \
    const int _bb = 2 * TILE16 + (buf) * TILE16 + (h) * HALF16 + wn * 32 + rbase; \
    _Pragma("unroll") \
    for (int _j = 0; _j < 4; ++_j) bfr[_j] = *(const bf16x8*)&lds[_bb + _j * 512]; \
  } while (0)
#define VMW4() asm volatile("s_waitcnt vmcnt(4)" ::: "memory")
#define BAR256() do { \
    asm volatile("" ::: "memory"); \
    __builtin_amdgcn_s_barrier(); \
    asm volatile("" ::: "memory"); \
  } while (0)
#define MFMA16(ih, af) do { \
    __builtin_amdgcn_s_setprio(1); \
    _Pragma("unroll") \
    for (int _i = 0; _i < 4; ++_i) \
      _Pragma("unroll") \
      for (int _j = 0; _j < 4; ++_j) \
        acc[(ih) * 4 + _i][_j] = __builtin_amdgcn_mfma_f32_16x16x32_bf16( \
            (af)[_i], bfr[_j], acc[(ih) * 4 + _i][_j], 0, 0, 0); \
    __builtin_amdgcn_s_setprio(0); \
  } while (0)
// One K-tile: compute buf c, stage next tile (cols kn) into buf n.
#define KTILE(c, n, kn) do { \
    { bf16x8 af[4]; RDA256(c, 0, 0, af); RDB256(c, 0); \
      SA256(n, kn, 0); MFMA16(0, af); } \
    { bf16x8 af[4]; RDA256(c, 0, 1, af); \
      SB256(n, kn, 0); VMW4(); BAR256(); MFMA16(1, af); } \
    { bf16x8 af[4]; RDA256(c, 1, 0, af); RDB256(c, 1); \
      SA256(n, kn, 1); MFMA16(0, af); } \
    { bf16x8 af[4]; RDA256(c, 1, 1, af); \
      SB256(n, kn, 1); VMW4(); BAR256(); MFMA16(1, af); } \
  } while (0)

  // prologue: stage tile 0 (8 loads), force its h0 halves, sync.
  SA256(0, 0, 0); SB256(0, 0, 0); SA256(0, 0, 1); SB256(0, 0, 1);
  VMW4();
  BAR256();

#pragma unroll 1
  for (int t = 0; t < 16; t += 2) {
    const int k1 = (t + 1) * 64;
    const int k2 = (t + 2 < 16) ? (t + 2) * 64 : 0;  // dummy restage keeps vmcnt uniform
    KTILE(0, 1, k1);
    KTILE(1, 0, k2);
  }
  // drain the dummy stages before LDS dealloc at endpgm
  asm volatile("s_waitcnt vmcnt(0)" ::: "memory");

#undef SA256
#undef SB256
#undef RDA256
#undef RDB256
#undef VMW4
#undef BAR256
#undef MFMA16
#undef KTILE

  // ---- epilogue: row-major store order, j innermost for full-sector writes.
  const int cn = lane & 15;
  const int rq = (lane >> 4) * 4;
  long colj[4]; float bvj[4], pvj[4];
#pragma unroll
  for (int j = 0; j < 4; ++j) {
    colj[j] = bn + wn + j * 16 + cn;
    bvj[j]  = bias[colj[j]];
    // Phases stored in revolutions: fold 1/(2*pi) into the phase scale.
    pvj[j]  = (MODE == 3) ? aux[colj[j]] * INV2PI : 0.0f;
  }
#pragma unroll
  for (int ii = 0; ii < 8; ++ii) {
#pragma unroll
    for (int r = 0; r < 4; ++r) {
      const long rowo = (bm + wm + ii * 16 + rq + r) * (long)DIMD;
#pragma unroll
      for (int j = 0; j < 4; ++j) {
        const float v = acc[ii][j][r] + bvj[j];
        if (MODE == 0) {
          Ob[rowo + colj[j]] = f2bf(v);
        } else if (MODE == 3) {
          Ob[rowo + colj[j]] = f2bf(tanh_fast(v) * pvj[j]);
        } else {
          Of[rowo + colj[j]] = v + resid[rowo + colj[j]];
        }
      }
    }
  }
}

// One block per chunk, 512 threads x 2 dims (8 waves/block -> 2 waves/SIMD).
// Phases arrive in REVOLUTIONS (scaled by 1/2pi in gemm256 MODE 3), so
// sin/cos are single native v_sin_f32/v_cos_f32 ops (|x|<=0.5 in-domain).
__global__ __launch_bounds__(512) void scan_ln_kernel(
    const unsigned short* __restrict__ V,  const unsigned short* __restrict__ KP,
    const unsigned short* __restrict__ QP,
    const float* __restrict__ lng, const float* __restrict__ lnb,
    unsigned short* __restrict__ out)
{
  __shared__ unsigned short ret_s[32][DIMD];   // 64 KB

  const int tid  = threadIdx.x;
  const int lane = tid & 63;
  const int wid  = tid >> 6;          // 0..7
  const long rowBase = (long)blockIdx.x * CHUNKLEN;
  const int d0 = tid * 2;

  const int c0 = lane * 8;
  const int c1 = 512 + lane * 8;
  float g0[8], be0[8], g1[8], be1[8];
#pragma unroll
  for (int j = 0; j < 8; ++j) {
    g0[j] = lng[c0 + j]; be0[j] = lnb[c0 + j];
    g1[j] = lng[c1 + j]; be1[j] = lnb[c1 + j];
  }

  float mr[2] = {0.f, 0.f};
  float mi[2] = {0.f, 0.f};

  for (int h = 0; h < 2; ++h) {
    // ---- phase 1: scan 32 steps, no barriers ----
#pragma unroll 4
    for (int tl = 0; tl < 32; ++tl) {
      const int t = h * 32 + tl;
      const long off = (rowBase + t) * DIMD + d0;
      const ushort2 v2 = *(const ushort2*)(V + off);
      const ushort2 k2 = *(const ushort2*)(KP + off);
      const ushort2 q2 = *(const ushort2*)(QP + off);
      const unsigned short va[2] = {v2.x, v2.y};
      const unsigned short ka[2] = {k2.x, k2.y};
      const unsigned short qa[2] = {q2.x, q2.y};
      unsigned short rv[2];
#pragma unroll
      for (int j = 0; j < 2; ++j) {
        const float v  = bf2f(va[j]);
        const float kp = bf2f(ka[j]);
        const float qp = bf2f(qa[j]);
        const float skp = __builtin_amdgcn_sinf(kp);
        const float ckp = __builtin_amdgcn_cosf(kp);
        const float sqp = __builtin_amdgcn_sinf(qp);
        const float cqp = __builtin_amdgcn_cosf(qp);
        mr[j] += v * ckp;
        mi[j] += v * skp;
        rv[j] = f2bf((mr[j] * cqp + mi[j] * sqp) * 0.03125f);
      }
      ushort2 o2; o2.x = rv[0]; o2.y = rv[1];
      *(ushort2*)&ret_s[tl][d0] = o2;
    }
    __syncthreads();

    // ---- phase 2: 4 rows per wave, shuffle-reduce LN ----
#pragma unroll 1
    for (int rr = 0; rr < 4; ++rr) {
      const int tl = wid * 4 + rr;
      const ushort8v a0 = *(const ushort8v*)&ret_s[tl][c0];
      const ushort8v a1 = *(const ushort8v*)&ret_s[tl][c1];
      float f0[8], f1[8];
      float s = 0.f, s2 = 0.f;
#pragma unroll
      for (int j = 0; j < 8; ++j) {
        f0[j] = bf2f(a0[j]); f1[j] = bf2f(a1[j]);
        s += f0[j] + f1[j];
        s2 += f0[j] * f0[j] + f1[j] * f1[j];
      }
#pragma unroll
      for (int o = 32; o > 0; o >>= 1) {
        s  += __shfl_xor(s,  o, 64);
        s2 += __shfl_xor(s2, o, 64);
      }
      const float mu  = s * (1.0f / DIMD);
      const float var = s2 * (1.0f / DIMD) - mu * mu;
      const float inv = rsqrtf(var + 1e-5f);
      ushort8v o0, o1;
#pragma unroll
      for (int j = 0; j < 8; ++j) {
        o0[j] = f2bf((f0[j] - mu) * inv * g0[j] + be0[j]);
        o1[j] = f2bf((f1[j] - mu) * inv * g1[j] + be1[j]);
      }
      const long gro = (rowBase + h * 32 + tl) * DIMD;
      *(ushort8v*)(out + gro + c0) = o0;
      *(ushort8v*)(out + gro + c1) = o1;
    }
    __syncthreads();
  }
}

extern "C" void kernel_launch(void* const* d_in, const int* in_sizes, int n_in,
                              void* d_out, int out_size, void* d_ws, size_t ws_size,
                              hipStream_t stream)
{
  const float* x   = (const float*)d_in[0];
  const float* Wk  = (const float*)d_in[1];
  const float* bk  = (const float*)d_in[2];
  const float* Wv  = (const float*)d_in[3];
  const float* bv  = (const float*)d_in[4];
  const float* Wq  = (const float*)d_in[5];
  const float* bq  = (const float*)d_in[6];
  const float* Wkp = (const float*)d_in[7];
  const float* bkp = (const float*)d_in[8];
  const float* Wqp = (const float*)d_in[9];
  const float* bqp = (const float*)d_in[10];
  const float* ph  = (const float*)d_in[11];
  const float* lng = (const float*)d_in[12];
  const float* lnb = (const float*)d_in[13];
  const float* Wo  = (const float*)d_in[14];
  const float* bo  = (const float*)d_in[15];
  float* out = (float*)d_out;

  const long NB = (long)NTOK * DIMD;
  const long DD = (long)DIMD * DIMD;
  const size_t required = (size_t)(4 * NB + 8 * DD) * sizeof(unsigned short)
                        + 2048 * sizeof(float);
  if (ws_size < required) return;

  unsigned short* S0   = (unsigned short*)d_ws;  // xb, later Rln
  unsigned short* SV   = S0   + NB;
  unsigned short* SKP  = SV   + NB;
  unsigned short* SQP  = SKP  + NB;
  unsigned short* Wvb  = SQP  + NB;
  unsigned short* Wob  = Wvb  + DD;
  unsigned short* Wkpb = Wob  + DD;
  unsigned short* Wqpb = Wkpb + DD;
  unsigned short* WkT  = Wqpb + DD;
  unsigned short* WqT  = WkT  + DD;
  unsigned short* Wkqb = WqT  + DD;
  unsigned short* Wqqb = Wkqb + DD;
  float* bkq = (float*)(Wqqb + DD);
  float* bqq = bkq + DIMD;

  // 1) fused prep: cvt (x, Wv, Wo, Wkp, Wqp) + transpose-cvt (Wk, Wq) + biases
  prep_kernel<<<dim3(16384 + 4 * 1024 + 512 + 512), dim3(256), 0, stream>>>(
      x, Wv, Wo, Wkp, Wqp, S0, Wvb, Wob, Wkpb, Wqpb,
      Wk, Wq, WkT, WqT, bk, bkp, bq, bqp, bkq, bqq);
  // 2) combined weights: Wkq = Wkp@Wk ; Wqq likewise (small -> 128^2 kernel)
  gemm_bt_kernel<1><<<dim3(DIMD / TN, DIMD / TM, 2), dim3(256), 0, stream>>>(
      Wkpb, Wqpb, WkT, WqT, Wkqb, Wqqb);
  // 3) V segment: SV = x@Wv^T + bv
  gemm256_kernel<0><<<dim3(4, NTOK / 256), dim3(512), 0, stream>>>(
      S0, Wvb, nullptr, nullptr, bv, nullptr, nullptr, nullptr,
      SV, nullptr, nullptr, nullptr, nullptr);
  // 4) phase segments: KP = tanh(x@Wkq^T+bkq)*ph/2pi | QP likewise
  gemm256_kernel<3><<<dim3(8, NTOK / 256), dim3(512), 0, stream>>>(
      S0, nullptr, Wkqb, Wqqb, nullptr, bkq, bqq, ph,
      nullptr, SKP, SQP, nullptr, nullptr);
  // 5) scan + layernorm -> Rln (reuses S0)
  scan_ln_kernel<<<dim3(NTOK / CHUNKLEN), dim3(512), 0, stream>>>(
      SV, SKP, SQP, lng, lnb, S0);
  // 6) out = Rln@Wo^T + bo + x  (fp32)
  gemm256_kernel<2><<<dim3(4, NTOK / 256), dim3(512), 0, stream>>>(
      S0, Wob, nullptr, nullptr, bo, nullptr, nullptr, nullptr,
      nullptr, nullptr, nullptr, out, x);
}